// Round 3
// baseline (874.933 us; speedup 1.0000x reference)
//
#include <hip/hip_runtime.h>
#include <hip/hip_bf16.h>

typedef unsigned int uint;
typedef unsigned short ushort;

#define NN 65536
#define NE 1048576
#define DD 128
#define TOTE (NE + NN)   // 1114112

__device__ __forceinline__ float b2f(ushort u) {
    uint v = ((uint)u) << 16; float f; __builtin_memcpy(&f, &v, 4); return f;
}
__device__ __forceinline__ ushort f2b(float f) {
    uint x; __builtin_memcpy(&x, &f, 4);
    uint r = (x + 0x7fffu + ((x >> 16) & 1u)) >> 16;
    return (ushort)r;
}

typedef __bf16 bf16x8 __attribute__((ext_vector_type(8)));
typedef float f32x4 __attribute__((ext_vector_type(4)));

// ---------- init: h fp32 copy + hb bf16 copy ----------
__global__ void k_x2hb(const float4* __restrict__ x, float4* __restrict__ h,
                       ushort* __restrict__ hb) {
    int i = blockIdx.x * 256 + threadIdx.x;   // NN*DD/4 elements
    float4 v = x[i];
    h[i] = v;
    ushort4 p;
    p.x = f2b(v.x); p.y = f2b(v.y); p.z = f2b(v.z); p.w = f2b(v.w);
    *(ushort4*)&hb[(size_t)i * 4] = p;
}

// ---------- mean of edge_attr ----------
__global__ void k_sum(const float* __restrict__ ea, float* __restrict__ sum) {
    __shared__ float red[256];
    int t = threadIdx.x;
    float s = 0.f;
    for (int i = blockIdx.x * 256 + t; i < NE; i += gridDim.x * 256) s += ea[i];
    red[t] = s; __syncthreads();
    for (int o = 128; o > 0; o >>= 1) { if (t < o) red[t] += red[t + o]; __syncthreads(); }
    if (t == 0) atomicAdd(sum, red[0]);
}

// ---------- CSR build ----------
__global__ void k_hist(const int* __restrict__ dst, int* __restrict__ cnt) {
    int e = blockIdx.x * 256 + threadIdx.x;
    int d = (e < NE) ? dst[e] : (e - NE);
    atomicAdd(&cnt[d], 1);
}

__global__ void k_scanA(const int* __restrict__ cnt, int* __restrict__ row_off, int* __restrict__ bsum) {
    __shared__ int tmp[256];
    int t = threadIdx.x, i = blockIdx.x * 256 + t;
    int v = cnt[i]; tmp[t] = v; __syncthreads();
    for (int off = 1; off < 256; off <<= 1) {
        int x = (t >= off) ? tmp[t - off] : 0;
        __syncthreads();
        tmp[t] += x;
        __syncthreads();
    }
    row_off[i] = tmp[t] - v;
    if (t == 255) bsum[blockIdx.x] = tmp[255];
}

__global__ void k_scanB(int* __restrict__ bsum) {
    __shared__ int tmp[256];
    int t = threadIdx.x;
    int v = bsum[t]; tmp[t] = v; __syncthreads();
    for (int off = 1; off < 256; off <<= 1) {
        int x = (t >= off) ? tmp[t - off] : 0;
        __syncthreads();
        tmp[t] += x;
        __syncthreads();
    }
    bsum[t] = tmp[t] - v;
}

__global__ void k_scanC(int* __restrict__ row_off, const int* __restrict__ bsum, int* __restrict__ cursor) {
    int i = blockIdx.x * 256 + threadIdx.x;
    int v = row_off[i] + bsum[blockIdx.x];
    row_off[i] = v;
    cursor[i] = v;
    if (i == 0) row_off[NN] = TOTE;
}

__global__ void k_scatter(const int* __restrict__ src, const int* __restrict__ dst,
                          const float* __restrict__ ea, const float* __restrict__ sum,
                          int* __restrict__ cursor, int* __restrict__ adj_src,
                          int* __restrict__ adj_dst, float* __restrict__ adj_ea) {
    int e = blockIdx.x * 256 + threadIdx.x;
    int s, d; float a;
    if (e < NE) { s = src[e]; d = dst[e]; a = ea[e]; }
    else        { s = e - NE; d = s;      a = sum[0] * (1.0f / NE); }
    int pos = atomicAdd(&cursor[d], 1);
    adj_src[pos] = s;
    adj_dst[pos] = d;
    adj_ea[pos] = a;
}

// ---------- all layers: transpose W (fp32 k-major -> bf16 n-major) ----------
__global__ void k_transpose(const float* __restrict__ Wl, const float* __restrict__ Wr,
                            ushort* __restrict__ WT) {
    // grid (128, 2, 3), block 128
    int k = blockIdx.x, n = threadIdx.x, lr = blockIdx.y, layer = blockIdx.z;
    const float* W = (lr ? Wr : Wl) + layer * 16384;
    WT[(layer * 2 + lr) * 16384 + n * 128 + k] = f2b(W[k * 128 + n]);
}

// ---------- dual GEMM: xl = h@Wl + bl, xr = h@Wr + br  (bf16 MFMA 16x16x32) ----------
#define LDA 136   // bf16 elems per A row in LDS (272B stride, 16B aligned)

__global__ __launch_bounds__(256) void k_gemm(const ushort* __restrict__ hb, const ushort* __restrict__ WT,
                                              const float* __restrict__ bl, const float* __restrict__ br,
                                              ushort* __restrict__ xl, ushort* __restrict__ xr) {
    __shared__ ushort A[64 * LDA];
    int t = threadIdx.x;
    int rowbase = blockIdx.x * 64;

    #pragma unroll
    for (int it = 0; it < 4; it++) {
        int idx = it * 256 + t;          // 1024 chunks of 8 bf16
        int r = idx >> 4, cc = (idx & 15) * 8;
        *(bf16x8*)&A[r * LDA + cc] = *(const bf16x8*)&hb[(size_t)(rowbase + r) * 128 + cc];
    }
    __syncthreads();

    int wave = t >> 6, lane = t & 63;
    int row16 = lane & 15, quad = lane >> 4;

    f32x4 accl[8], accr[8];
    for (int i = 0; i < 8; i++) {
        accl[i] = (f32x4){0.f, 0.f, 0.f, 0.f};
        accr[i] = (f32x4){0.f, 0.f, 0.f, 0.f};
    }

    for (int ks = 0; ks < 4; ks++) {
        bf16x8 a = *(const bf16x8*)&A[(wave * 16 + row16) * LDA + ks * 32 + quad * 8];
        for (int tc = 0; tc < 8; tc++) {
            int coln = tc * 16 + row16;                 // B fragment: n = lane&15
            bf16x8 b_l = *(const bf16x8*)&WT[coln * 128 + ks * 32 + quad * 8];
            bf16x8 b_r = *(const bf16x8*)&WT[16384 + coln * 128 + ks * 32 + quad * 8];
            accl[tc] = __builtin_amdgcn_mfma_f32_16x16x32_bf16(a, b_l, accl[tc], 0, 0, 0);
            accr[tc] = __builtin_amdgcn_mfma_f32_16x16x32_bf16(a, b_r, accr[tc], 0, 0, 0);
        }
    }

    for (int tc = 0; tc < 8; tc++) {
        int col = tc * 16 + row16;                      // C/D: col = lane&15
        float bbl = bl[col], bbr = br[col];
        for (int r = 0; r < 4; r++) {
            int row = rowbase + wave * 16 + quad * 4 + r;   // C/D: row = quad*4 + reg
            size_t o = (size_t)row * 128 + col;
            xl[o] = f2b(accl[tc][r] + bbl);
            xr[o] = f2b(accr[tc][r] + bbr);
        }
    }
}

// ---------- edge-parallel attention logits ----------
// 16 lanes per edge, each lane handles 8 channels. Writes a[e,h] CSR-indexed.
template<int H>
__global__ __launch_bounds__(256) void k_edge(
    const ushort* __restrict__ xl, const ushort* __restrict__ xr,
    const int* __restrict__ adj_src, const int* __restrict__ adj_dst,
    const float* __restrict__ adj_ea,
    const float* __restrict__ We, const float* __restrict__ att,
    float* __restrict__ adj_a)
{
    int t = threadIdx.x;
    int l = t & 15;
    int e = blockIdx.x * 16 + (t >> 4);
    int c = l * 8;

    float we[8], at[8];
    #pragma unroll
    for (int j = 0; j < 8; j++) { we[j] = We[c + j]; at[j] = att[c + j]; }

    int src = adj_src[e], dst = adj_dst[e];
    float ea = adj_ea[e];
    bf16x8 xs = *(const bf16x8*)&xl[(size_t)src * 128 + c];
    bf16x8 xd = *(const bf16x8*)&xr[(size_t)dst * 128 + c];

    float s = 0.f;
    #pragma unroll
    for (int j = 0; j < 8; j++) {
        float m = (float)xs[j] + (float)xd[j] + ea * we[j];
        m = fmaxf(m, 0.2f * m);          // leaky_relu(0.2)
        s = fmaf(m, at[j], s);
    }
    const int Q = 16 / H;                // lanes per head
    #pragma unroll
    for (int off = 1; off < Q; off <<= 1) s += __shfl_xor(s, off);
    if ((l & (Q - 1)) == 0) adj_a[(size_t)e * H + (l / Q)] = s;
}

// ---------- per-node: softmax over segment + aggregation + LN (+GELU) + residual ----------
template<int H>
__global__ __launch_bounds__(256) void k_node2(
    const ushort* __restrict__ xl, const float* __restrict__ adj_a,
    const int* __restrict__ row_off, const int* __restrict__ adj_src,
    const float* __restrict__ bias, const float* __restrict__ ln_g, const float* __restrict__ ln_b,
    float* __restrict__ h, ushort* __restrict__ hb, int apply_gelu)
{
    int wave = threadIdx.x >> 6, lane = threadIdx.x & 63;
    int n = blockIdx.x * 4 + wave;
    int i16 = lane & 15, g = lane >> 4;
    int c0 = 2 * lane, c1 = c0 + 1;
    int s0 = row_off[n], s1 = row_off[n + 1];

    // ---- pass 1: per-head running max & exp-sum (slot-parallel, 16 slots/round) ----
    float m = -1e30f, lsum = 0.f;
    for (int base = s0; base < s1; base += 16) {
        int slot = base + i16;
        float a = -1e30f;
        if (slot < s1) a = (H == 4) ? adj_a[(size_t)slot * 4 + g] : adj_a[slot];
        float nm = fmaxf(m, a);
        lsum = lsum * __expf(m - nm) + __expf(a - nm);
        m = nm;
    }
    #pragma unroll
    for (int off = 1; off < 16; off <<= 1) {
        float mo = __shfl_xor(m, off), lo = __shfl_xor(lsum, off);
        float nm = fmaxf(m, mo);
        lsum = lsum * __expf(m - nm) + lo * __expf(mo - nm);
        m = nm;
    }
    float inv_l = 1.0f / (lsum + 1e-16f);

    // ---- pass 2: weighted aggregation, chunks of 64 slots ----
    float acc0 = 0.f, acc1 = 0.f;
    for (int base = s0; base < s1; base += 64) {
        int cnt = min(64, s1 - base);
        float al[4];
        #pragma unroll
        for (int k = 0; k < 4; k++) {
            int slot = base + k * 16 + i16;
            float a = 0.f;
            if (slot < s1) a = (H == 4) ? adj_a[(size_t)slot * 4 + g] : adj_a[slot];
            al[k] = (slot < s1) ? __expf(a - m) * inv_l : 0.f;
        }
        int srcl = (base + lane < s1) ? adj_src[base + lane] : 0;
        #pragma unroll
        for (int k = 0; k < 4; k++) {
            if (k * 16 >= cnt) break;                 // wave-uniform
            int lim = min(16, cnt - k * 16);
            for (int jj = 0; jj < lim; jj++) {
                float alpha = __shfl(al[k], (lane & 48) | jj);   // head-matched source lane
                int src = __shfl(srcl, k * 16 + jj);
                uint u = *(const uint*)&xl[(size_t)src * 128 + c0];
                acc0 = fmaf(alpha, b2f((ushort)u), acc0);
                acc1 = fmaf(alpha, b2f((ushort)(u >> 16)), acc1);
            }
        }
    }

    float o0 = acc0 + bias[c0];
    float o1 = acc1 + bias[c1];

    // LayerNorm over 128 channels (2 per lane)
    float s = o0 + o1;
    #pragma unroll
    for (int off = 1; off < 64; off <<= 1) s += __shfl_xor(s, off);
    float mu = s * (1.f / 128.f);
    float d0 = o0 - mu, d1 = o1 - mu;
    float v = d0 * d0 + d1 * d1;
    #pragma unroll
    for (int off = 1; off < 64; off <<= 1) v += __shfl_xor(v, off);
    float rstd = rsqrtf(v * (1.f / 128.f) + 1e-5f);
    o0 = d0 * rstd * ln_g[c0] + ln_b[c0];
    o1 = d1 * rstd * ln_g[c1] + ln_b[c1];

    if (apply_gelu) {
        o0 = 0.5f * o0 * (1.f + erff(o0 * 0.70710678118f));
        o1 = 0.5f * o1 * (1.f + erff(o1 * 0.70710678118f));
    }

    float2 hv = *(float2*)&h[(size_t)n * 128 + c0];
    hv.x += o0; hv.y += o1;
    *(float2*)&h[(size_t)n * 128 + c0] = hv;
    uint pk = (uint)f2b(hv.x) | ((uint)f2b(hv.y) << 16);
    *(uint*)&hb[(size_t)n * 128 + c0] = pk;
}

// ---------- final: drop last node per graph, emit fp32 ----------
__global__ void k_out(const float* __restrict__ h, float* __restrict__ out) {
    int o = blockIdx.x * 256 + threadIdx.x;   // grid covers 128*511*128 exactly
    int c = o & 127;
    int row = o >> 7;
    int g = row / 511;
    int r = row - g * 511;
    out[o] = h[(size_t)(g * 512 + r) * 128 + c];
}

extern "C" void kernel_launch(void* const* d_in, const int* in_sizes, int n_in,
                              void* d_out, int out_size, void* d_ws, size_t ws_size,
                              hipStream_t stream) {
    const float* x        = (const float*)d_in[0];
    const int*   edge_src = (const int*)d_in[1];
    const int*   edge_dst = (const int*)d_in[2];
    const float* edge_attr= (const float*)d_in[3];
    const float* Wl       = (const float*)d_in[4];
    const float* bl       = (const float*)d_in[5];
    const float* Wr       = (const float*)d_in[6];
    const float* br       = (const float*)d_in[7];
    const float* We       = (const float*)d_in[8];
    const float* att      = (const float*)d_in[9];
    const float* bias_p   = (const float*)d_in[10];
    const float* ln_g     = (const float*)d_in[11];
    const float* ln_b     = (const float*)d_in[12];
    float* out = (float*)d_out;

    char* ws = (char*)d_ws;
    float*  h       = (float*)(ws + 0);                 // 33,554,432
    ushort* hb      = (ushort*)(ws + 33554432);         // 16,777,216
    ushort* xl      = (ushort*)(ws + 50331648);         // 16,777,216
    ushort* xr      = (ushort*)(ws + 67108864);         // 16,777,216
    int*    adj_src = (int*)(ws + 83886080);            //  4,456,448
    int*    adj_dst = (int*)(ws + 88342528);            //  4,456,448
    float*  adj_ea  = (float*)(ws + 92798976);          //  4,456,448
    int*    row_off = (int*)(ws + 97255424);            //    262,148 (+pad)
    int*    cnt     = (int*)(ws + 97517824);            //    262,144 (also cursor)
    int*    bsum    = (int*)(ws + 97779968);            //      1,024
    float*  sumbuf  = (float*)(ws + 97780992);          //          4 (+pad)
    ushort* WT      = (ushort*)(ws + 97781248);         //    196,608 (3 layers x 2)
    // attention logits scratch lives in d_out (dead until k_out): TOTE*4 floats = 17.8MB <= 33.4MB
    float*  adj_a   = (float*)d_out;

    // init
    k_x2hb<<<(NN * DD / 4) / 256, 256, 0, stream>>>((const float4*)x, (float4*)h, hb);
    hipMemsetAsync(cnt, 0, NN * sizeof(int), stream);
    hipMemsetAsync(sumbuf, 0, sizeof(float), stream);
    k_sum<<<256, 256, 0, stream>>>(edge_attr, sumbuf);

    // CSR by dst (edges + self loops)
    k_hist<<<TOTE / 256, 256, 0, stream>>>(edge_dst, cnt);
    k_scanA<<<NN / 256, 256, 0, stream>>>(cnt, row_off, bsum);
    k_scanB<<<1, 256, 0, stream>>>(bsum);
    k_scanC<<<NN / 256, 256, 0, stream>>>(row_off, bsum, cnt);
    k_scatter<<<TOTE / 256, 256, 0, stream>>>(edge_src, edge_dst, edge_attr, sumbuf,
                                              cnt, adj_src, adj_dst, adj_ea);

    // weights for all 3 layers
    k_transpose<<<dim3(128, 2, 3), 128, 0, stream>>>(Wl, Wr, WT);

    // 3 GATv2 layers
    for (int i = 0; i < 3; i++) {
        k_gemm<<<NN / 64, 256, 0, stream>>>(hb, WT + i * 32768, bl + i * 128, br + i * 128, xl, xr);
        if (i < 2) {
            k_edge<4><<<TOTE / 16, 256, 0, stream>>>(xl, xr, adj_src, adj_dst, adj_ea,
                                                     We + i * 128, att + i * 128, adj_a);
            k_node2<4><<<NN / 4, 256, 0, stream>>>(xl, adj_a, row_off, adj_src,
                                                   bias_p + i * 128, ln_g + i * 128, ln_b + i * 128,
                                                   h, hb, 1);
        } else {
            k_edge<1><<<TOTE / 16, 256, 0, stream>>>(xl, xr, adj_src, adj_dst, adj_ea,
                                                     We + i * 128, att + i * 128, adj_a);
            k_node2<1><<<NN / 4, 256, 0, stream>>>(xl, adj_a, row_off, adj_src,
                                                   bias_p + i * 128, ln_g + i * 128, ln_b + i * 128,
                                                   h, hb, 0);
        }
    }

    // output: (128, 511, 128) fp32
    k_out<<<(128 * 511 * 128) / 256, 256, 0, stream>>>(h, out);
}

// Round 4
// 846.223 us; speedup vs baseline: 1.0339x; 1.0339x over previous
//
#include <hip/hip_runtime.h>
#include <hip/hip_bf16.h>

typedef unsigned int uint;
typedef unsigned short ushort;

#define NN 65536
#define NE 1048576
#define DD 128
#define TOTE (NE + NN)   // 1114112

__device__ __forceinline__ float b2f(ushort u) {
    uint v = ((uint)u) << 16; float f; __builtin_memcpy(&f, &v, 4); return f;
}
__device__ __forceinline__ ushort f2b(float f) {
    uint x; __builtin_memcpy(&x, &f, 4);
    uint r = (x + 0x7fffu + ((x >> 16) & 1u)) >> 16;
    return (ushort)r;
}

typedef __bf16 bf16x8 __attribute__((ext_vector_type(8)));
typedef float f32x4 __attribute__((ext_vector_type(4)));

// ---------- init: h fp32 copy + hb bf16 copy ----------
__global__ void k_x2hb(const float4* __restrict__ x, float4* __restrict__ h,
                       ushort* __restrict__ hb) {
    int i = blockIdx.x * 256 + threadIdx.x;   // NN*DD/4 elements
    float4 v = x[i];
    h[i] = v;
    ushort4 p;
    p.x = f2b(v.x); p.y = f2b(v.y); p.z = f2b(v.z); p.w = f2b(v.w);
    *(ushort4*)&hb[(size_t)i * 4] = p;
}

// ---------- mean of edge_attr ----------
__global__ void k_sum(const float* __restrict__ ea, float* __restrict__ sum) {
    __shared__ float red[256];
    int t = threadIdx.x;
    float s = 0.f;
    for (int i = blockIdx.x * 256 + t; i < NE; i += gridDim.x * 256) s += ea[i];
    red[t] = s; __syncthreads();
    for (int o = 128; o > 0; o >>= 1) { if (t < o) red[t] += red[t + o]; __syncthreads(); }
    if (t == 0) atomicAdd(sum, red[0]);
}

// ---------- CSR build ----------
__global__ void k_hist(const int* __restrict__ dst, int* __restrict__ cnt) {
    int e = blockIdx.x * 256 + threadIdx.x;
    int d = (e < NE) ? dst[e] : (e - NE);
    atomicAdd(&cnt[d], 1);
}

__global__ void k_scanA(const int* __restrict__ cnt, int* __restrict__ row_off, int* __restrict__ bsum) {
    __shared__ int tmp[256];
    int t = threadIdx.x, i = blockIdx.x * 256 + t;
    int v = cnt[i]; tmp[t] = v; __syncthreads();
    for (int off = 1; off < 256; off <<= 1) {
        int x = (t >= off) ? tmp[t - off] : 0;
        __syncthreads();
        tmp[t] += x;
        __syncthreads();
    }
    row_off[i] = tmp[t] - v;
    if (t == 255) bsum[blockIdx.x] = tmp[255];
}

__global__ void k_scanB(int* __restrict__ bsum) {
    __shared__ int tmp[256];
    int t = threadIdx.x;
    int v = bsum[t]; tmp[t] = v; __syncthreads();
    for (int off = 1; off < 256; off <<= 1) {
        int x = (t >= off) ? tmp[t - off] : 0;
        __syncthreads();
        tmp[t] += x;
        __syncthreads();
    }
    bsum[t] = tmp[t] - v;
}

__global__ void k_scanC(int* __restrict__ row_off, const int* __restrict__ bsum, int* __restrict__ cursor) {
    int i = blockIdx.x * 256 + threadIdx.x;
    int v = row_off[i] + bsum[blockIdx.x];
    row_off[i] = v;
    cursor[i] = v;
    if (i == 0) row_off[NN] = TOTE;
}

__global__ void k_scatter(const int* __restrict__ src, const int* __restrict__ dst,
                          const float* __restrict__ ea, const float* __restrict__ sum,
                          int* __restrict__ cursor, int* __restrict__ adj_src,
                          float* __restrict__ adj_ea) {
    int e = blockIdx.x * 256 + threadIdx.x;
    int s, d; float a;
    if (e < NE) { s = src[e]; d = dst[e]; a = ea[e]; }
    else        { s = e - NE; d = s;      a = sum[0] * (1.0f / NE); }
    int pos = atomicAdd(&cursor[d], 1);
    adj_src[pos] = s;
    adj_ea[pos] = a;
}

// ---------- all layers: transpose W (fp32 k-major -> bf16 n-major) ----------
__global__ void k_transpose(const float* __restrict__ Wl, const float* __restrict__ Wr,
                            ushort* __restrict__ WT) {
    // grid (128, 2, 3), block 128
    int k = blockIdx.x, n = threadIdx.x, lr = blockIdx.y, layer = blockIdx.z;
    const float* W = (lr ? Wr : Wl) + layer * 16384;
    WT[(layer * 2 + lr) * 16384 + n * 128 + k] = f2b(W[k * 128 + n]);
}

// ---------- dual GEMM: xl = h@Wl + bl, xr = h@Wr + br  (bf16 MFMA 16x16x32) ----------
#define LDA 136   // bf16 elems per A row in LDS (272B stride, 16B aligned)

__global__ __launch_bounds__(256) void k_gemm(const ushort* __restrict__ hb, const ushort* __restrict__ WT,
                                              const float* __restrict__ bl, const float* __restrict__ br,
                                              ushort* __restrict__ xl, ushort* __restrict__ xr) {
    __shared__ ushort A[64 * LDA];
    int t = threadIdx.x;
    int rowbase = blockIdx.x * 64;

    #pragma unroll
    for (int it = 0; it < 4; it++) {
        int idx = it * 256 + t;          // 1024 chunks of 8 bf16
        int r = idx >> 4, cc = (idx & 15) * 8;
        *(bf16x8*)&A[r * LDA + cc] = *(const bf16x8*)&hb[(size_t)(rowbase + r) * 128 + cc];
    }
    __syncthreads();

    int wave = t >> 6, lane = t & 63;
    int row16 = lane & 15, quad = lane >> 4;

    f32x4 accl[8], accr[8];
    for (int i = 0; i < 8; i++) {
        accl[i] = (f32x4){0.f, 0.f, 0.f, 0.f};
        accr[i] = (f32x4){0.f, 0.f, 0.f, 0.f};
    }

    for (int ks = 0; ks < 4; ks++) {
        bf16x8 a = *(const bf16x8*)&A[(wave * 16 + row16) * LDA + ks * 32 + quad * 8];
        for (int tc = 0; tc < 8; tc++) {
            int coln = tc * 16 + row16;                 // B fragment: n = lane&15
            bf16x8 b_l = *(const bf16x8*)&WT[coln * 128 + ks * 32 + quad * 8];
            bf16x8 b_r = *(const bf16x8*)&WT[16384 + coln * 128 + ks * 32 + quad * 8];
            accl[tc] = __builtin_amdgcn_mfma_f32_16x16x32_bf16(a, b_l, accl[tc], 0, 0, 0);
            accr[tc] = __builtin_amdgcn_mfma_f32_16x16x32_bf16(a, b_r, accr[tc], 0, 0, 0);
        }
    }

    for (int tc = 0; tc < 8; tc++) {
        int col = tc * 16 + row16;                      // C/D: col = lane&15
        float bbl = bl[col], bbr = br[col];
        for (int r = 0; r < 4; r++) {
            int row = rowbase + wave * 16 + quad * 4 + r;   // C/D: row = quad*4 + reg
            size_t o = (size_t)row * 128 + col;
            xl[o] = f2b(accl[tc][r] + bbl);
            xr[o] = f2b(accr[tc][r] + bbr);
        }
    }
}

// ---------- fused attention: logits + softmax + aggregation + LN (+GELU) + residual ----------
// One wave per node. Chunks of 64 edges. Logit pass: 8 lanes/edge, 16 ch/lane
// (reg-cached We/att/xr). Aggregation re-reads xl rows (L1/L2-hot from logit pass).
template<int H>
__global__ __launch_bounds__(256) void k_attn(
    const ushort* __restrict__ xl, const ushort* __restrict__ xr,
    const int* __restrict__ row_off, const int* __restrict__ adj_src,
    const float* __restrict__ adj_ea,
    const float* __restrict__ We, const float* __restrict__ att,
    const float* __restrict__ bias, const float* __restrict__ ln_g, const float* __restrict__ ln_b,
    float* __restrict__ h, ushort* __restrict__ hb, int apply_gelu)
{
    __shared__ int   src_s[4][64];
    __shared__ float ea_s[4][64];
    __shared__ float a_s[4][64 * 4];
    __shared__ float es_s[4][64 * 4];

    int wave = threadIdx.x >> 6, lane = threadIdx.x & 63;
    int n = blockIdx.x * 4 + wave;
    int cl = lane & 7;          // channel block (logit pass): ch [16*cl, 16*cl+16)
    int c16 = cl * 16;
    int c0 = 2 * lane;          // aggregation channels {c0, c0+1}
    int g = lane >> 4;          // head for aggregation lanes (H=4)

    // register caches: We/att (fp32 global) + xr row of this node (bf16)
    float we[16], at[16], xrl[16];
    #pragma unroll
    for (int k = 0; k < 16; k++) { we[k] = We[c16 + k]; at[k] = att[c16 + k]; }
    {
        bf16x8 r0 = *(const bf16x8*)&xr[(size_t)n * 128 + c16];
        bf16x8 r1 = *(const bf16x8*)&xr[(size_t)n * 128 + c16 + 8];
        #pragma unroll
        for (int k = 0; k < 8; k++) { xrl[k] = (float)r0[k]; xrl[8 + k] = (float)r1[k]; }
    }

    int s0 = row_off[n], s1 = row_off[n + 1];

    float m_run = -1e30f, l_run = 0.f, acc0 = 0.f, acc1 = 0.f;

    for (int base = s0; base < s1; base += 64) {
        int cnt = min(64, s1 - base);

        // stage edge data (per-wave LDS slice; all hazards are within-wave)
        if (lane < cnt) {
            src_s[wave][lane] = adj_src[base + lane];
            ea_s[wave][lane]  = adj_ea[base + lane];
        }

        // ---- logits: 8 edges per iteration ----
        for (int it = 0; it * 8 < cnt; ++it) {
            int j = it * 8 + (lane >> 3);
            bool valid = j < cnt;
            int jc = valid ? j : 0;
            int sj = src_s[wave][jc];
            float eaj = ea_s[wave][jc];
            const ushort* rp = &xl[(size_t)sj * 128 + c16];
            bf16x8 x0 = *(const bf16x8*)rp;
            bf16x8 x1 = *(const bf16x8*)(rp + 8);
            float s = 0.f;
            #pragma unroll
            for (int k = 0; k < 8; k++) {
                float m = fmaf(eaj, we[k], xrl[k]) + (float)x0[k];
                m = fmaxf(m, 0.2f * m);
                s = fmaf(m, at[k], s);
            }
            #pragma unroll
            for (int k = 0; k < 8; k++) {
                float m = fmaf(eaj, we[8 + k], xrl[8 + k]) + (float)x1[k];
                m = fmaxf(m, 0.2f * m);
                s = fmaf(m, at[8 + k], s);
            }
            if (H == 4) {
                s += __shfl_xor(s, 1);                   // 2 lanes (32ch) = one head
                if (valid && ((cl & 1) == 0)) a_s[wave][j * 4 + (cl >> 1)] = s;
            } else {
                s += __shfl_xor(s, 1); s += __shfl_xor(s, 2); s += __shfl_xor(s, 4);
                if (valid && cl == 0) a_s[wave][j] = s;
            }
        }

        // ---- chunk softmax stats (slot-parallel) ----
        float m_c, l_c;
        if (H == 4) {
            int i16 = lane & 15;
            float a0 = (i16      < cnt) ? a_s[wave][(i16     ) * 4 + g] : -1e30f;
            float a1 = (i16 + 16 < cnt) ? a_s[wave][(i16 + 16) * 4 + g] : -1e30f;
            float a2 = (i16 + 32 < cnt) ? a_s[wave][(i16 + 32) * 4 + g] : -1e30f;
            float a3 = (i16 + 48 < cnt) ? a_s[wave][(i16 + 48) * 4 + g] : -1e30f;
            m_c = fmaxf(fmaxf(a0, a1), fmaxf(a2, a3));
            #pragma unroll
            for (int off = 1; off < 16; off <<= 1) m_c = fmaxf(m_c, __shfl_xor(m_c, off));
            float e0 = __expf(a0 - m_c), e1 = __expf(a1 - m_c);
            float e2 = __expf(a2 - m_c), e3 = __expf(a3 - m_c);
            if (i16      < cnt) es_s[wave][(i16     ) * 4 + g] = e0;
            if (i16 + 16 < cnt) es_s[wave][(i16 + 16) * 4 + g] = e1;
            if (i16 + 32 < cnt) es_s[wave][(i16 + 32) * 4 + g] = e2;
            if (i16 + 48 < cnt) es_s[wave][(i16 + 48) * 4 + g] = e3;
            l_c = e0 + e1 + e2 + e3;
            #pragma unroll
            for (int off = 1; off < 16; off <<= 1) l_c += __shfl_xor(l_c, off);
        } else {
            float a0 = (lane < cnt) ? a_s[wave][lane] : -1e30f;
            m_c = a0;
            #pragma unroll
            for (int off = 1; off < 64; off <<= 1) m_c = fmaxf(m_c, __shfl_xor(m_c, off));
            float e0 = __expf(a0 - m_c);
            if (lane < cnt) es_s[wave][lane] = e0;
            l_c = (lane < cnt) ? e0 : 0.f;
            #pragma unroll
            for (int off = 1; off < 64; off <<= 1) l_c += __shfl_xor(l_c, off);
        }
        float nm = fmaxf(m_run, m_c);
        float corr = __expf(m_run - nm);
        float ss = __expf(m_c - nm);
        l_run = l_run * corr + l_c * ss;
        m_run = nm;

        // ---- aggregation (rows are L1/L2-hot from logit pass) ----
        float sub0 = 0.f, sub1 = 0.f;
        for (int j = 0; j < cnt; ++j) {
            float esv = (H == 4) ? es_s[wave][j * 4 + g] : es_s[wave][j];
            int sj = src_s[wave][j];
            uint u = *(const uint*)&xl[(size_t)sj * 128 + c0];
            sub0 = fmaf(esv, b2f((ushort)u), sub0);
            sub1 = fmaf(esv, b2f((ushort)(u >> 16)), sub1);
        }
        acc0 = acc0 * corr + sub0 * ss;
        acc1 = acc1 * corr + sub1 * ss;
    }

    float inv = 1.0f / (l_run + 1e-16f);
    float o0 = acc0 * inv + bias[c0];
    float o1 = acc1 * inv + bias[c0 + 1];

    // LayerNorm over 128 channels (2 per lane)
    float s = o0 + o1;
    #pragma unroll
    for (int off = 1; off < 64; off <<= 1) s += __shfl_xor(s, off);
    float mu = s * (1.f / 128.f);
    float d0 = o0 - mu, d1 = o1 - mu;
    float v = d0 * d0 + d1 * d1;
    #pragma unroll
    for (int off = 1; off < 64; off <<= 1) v += __shfl_xor(v, off);
    float rstd = rsqrtf(v * (1.f / 128.f) + 1e-5f);
    o0 = d0 * rstd * ln_g[c0] + ln_b[c0];
    o1 = d1 * rstd * ln_g[c0 + 1] + ln_b[c0 + 1];

    if (apply_gelu) {
        o0 = 0.5f * o0 * (1.f + erff(o0 * 0.70710678118f));
        o1 = 0.5f * o1 * (1.f + erff(o1 * 0.70710678118f));
    }

    float2 hv = *(float2*)&h[(size_t)n * 128 + c0];
    hv.x += o0; hv.y += o1;
    *(float2*)&h[(size_t)n * 128 + c0] = hv;
    uint pk = (uint)f2b(hv.x) | ((uint)f2b(hv.y) << 16);
    *(uint*)&hb[(size_t)n * 128 + c0] = pk;
}

// ---------- final: drop last node per graph, emit fp32 ----------
__global__ void k_out(const float* __restrict__ h, float* __restrict__ out) {
    int o = blockIdx.x * 256 + threadIdx.x;   // grid covers 128*511*128 exactly
    int c = o & 127;
    int row = o >> 7;
    int g = row / 511;
    int r = row - g * 511;
    out[o] = h[(size_t)(g * 512 + r) * 128 + c];
}

extern "C" void kernel_launch(void* const* d_in, const int* in_sizes, int n_in,
                              void* d_out, int out_size, void* d_ws, size_t ws_size,
                              hipStream_t stream) {
    const float* x        = (const float*)d_in[0];
    const int*   edge_src = (const int*)d_in[1];
    const int*   edge_dst = (const int*)d_in[2];
    const float* edge_attr= (const float*)d_in[3];
    const float* Wl       = (const float*)d_in[4];
    const float* bl       = (const float*)d_in[5];
    const float* Wr       = (const float*)d_in[6];
    const float* br       = (const float*)d_in[7];
    const float* We       = (const float*)d_in[8];
    const float* att      = (const float*)d_in[9];
    const float* bias_p   = (const float*)d_in[10];
    const float* ln_g     = (const float*)d_in[11];
    const float* ln_b     = (const float*)d_in[12];
    float* out = (float*)d_out;

    char* ws = (char*)d_ws;
    float*  h       = (float*)(ws + 0);                 // 33,554,432
    ushort* hb      = (ushort*)(ws + 33554432);         // 16,777,216
    ushort* xl      = (ushort*)(ws + 50331648);         // 16,777,216
    ushort* xr      = (ushort*)(ws + 67108864);         // 16,777,216
    int*    adj_src = (int*)(ws + 83886080);            //  4,456,448
    float*  adj_ea  = (float*)(ws + 88342528);          //  4,456,448
    int*    row_off = (int*)(ws + 92798976);            //    262,148 (+pad)
    int*    cnt     = (int*)(ws + 93061376);            //    262,144 (also cursor)
    int*    bsum    = (int*)(ws + 93323520);            //      1,024
    float*  sumbuf  = (float*)(ws + 93324544);          //          4 (+pad)
    ushort* WT      = (ushort*)(ws + 93324800);         //    196,608 (3 layers x 2)

    // init
    k_x2hb<<<(NN * DD / 4) / 256, 256, 0, stream>>>((const float4*)x, (float4*)h, hb);
    hipMemsetAsync(cnt, 0, NN * sizeof(int), stream);
    hipMemsetAsync(sumbuf, 0, sizeof(float), stream);
    k_sum<<<256, 256, 0, stream>>>(edge_attr, sumbuf);

    // CSR by dst (edges + self loops)
    k_hist<<<TOTE / 256, 256, 0, stream>>>(edge_dst, cnt);
    k_scanA<<<NN / 256, 256, 0, stream>>>(cnt, row_off, bsum);
    k_scanB<<<1, 256, 0, stream>>>(bsum);
    k_scanC<<<NN / 256, 256, 0, stream>>>(row_off, bsum, cnt);
    k_scatter<<<TOTE / 256, 256, 0, stream>>>(edge_src, edge_dst, edge_attr, sumbuf,
                                              cnt, adj_src, adj_ea);

    // weights for all 3 layers
    k_transpose<<<dim3(128, 2, 3), 128, 0, stream>>>(Wl, Wr, WT);

    // 3 GATv2 layers
    for (int i = 0; i < 3; i++) {
        k_gemm<<<NN / 64, 256, 0, stream>>>(hb, WT + i * 32768, bl + i * 128, br + i * 128, xl, xr);
        if (i < 2) {
            k_attn<4><<<NN / 4, 256, 0, stream>>>(xl, xr, row_off, adj_src, adj_ea,
                                                  We + i * 128, att + i * 128, bias_p + i * 128,
                                                  ln_g + i * 128, ln_b + i * 128, h, hb, 1);
        } else {
            k_attn<1><<<NN / 4, 256, 0, stream>>>(xl, xr, row_off, adj_src, adj_ea,
                                                  We + i * 128, att + i * 128, bias_p + i * 128,
                                                  ln_g + i * 128, ln_b + i * 128, h, hb, 0);
        }
    }

    // output: (128, 511, 128) fp32
    k_out<<<(128 * 511 * 128) / 256, 256, 0, stream>>>(h, out);
}

// Round 5
// 694.385 us; speedup vs baseline: 1.2600x; 1.2187x over previous
//
#include <hip/hip_runtime.h>
#include <hip/hip_bf16.h>

typedef unsigned int uint;
typedef unsigned short ushort;

#define NN 65536
#define NE 1048576
#define DD 128
#define TOTE (NE + NN)   // 1114112

__device__ __forceinline__ float b2f(ushort u) {
    uint v = ((uint)u) << 16; float f; __builtin_memcpy(&f, &v, 4); return f;
}
__device__ __forceinline__ ushort f2b(float f) {
    uint x; __builtin_memcpy(&x, &f, 4);
    uint r = (x + 0x7fffu + ((x >> 16) & 1u)) >> 16;
    return (ushort)r;
}

typedef __bf16 bf16x8 __attribute__((ext_vector_type(8)));
typedef float f32x4 __attribute__((ext_vector_type(4)));

// ---------- init: h fp32 copy + hb bf16 copy ----------
__global__ void k_x2hb(const float4* __restrict__ x, float4* __restrict__ h,
                       ushort* __restrict__ hb) {
    int i = blockIdx.x * 256 + threadIdx.x;   // NN*DD/4 elements
    float4 v = x[i];
    h[i] = v;
    ushort4 p;
    p.x = f2b(v.x); p.y = f2b(v.y); p.z = f2b(v.z); p.w = f2b(v.w);
    *(ushort4*)&hb[(size_t)i * 4] = p;
}

// ---------- mean of edge_attr ----------
__global__ void k_sum(const float* __restrict__ ea, float* __restrict__ sum) {
    __shared__ float red[256];
    int t = threadIdx.x;
    float s = 0.f;
    for (int i = blockIdx.x * 256 + t; i < NE; i += gridDim.x * 256) s += ea[i];
    red[t] = s; __syncthreads();
    for (int o = 128; o > 0; o >>= 1) { if (t < o) red[t] += red[t + o]; __syncthreads(); }
    if (t == 0) atomicAdd(sum, red[0]);
}

// ---------- CSR build ----------
__global__ void k_hist(const int* __restrict__ dst, int* __restrict__ cnt) {
    int e = blockIdx.x * 256 + threadIdx.x;
    int d = (e < NE) ? dst[e] : (e - NE);
    atomicAdd(&cnt[d], 1);
}

__global__ void k_scanA(const int* __restrict__ cnt, int* __restrict__ row_off, int* __restrict__ bsum) {
    __shared__ int tmp[256];
    int t = threadIdx.x, i = blockIdx.x * 256 + t;
    int v = cnt[i]; tmp[t] = v; __syncthreads();
    for (int off = 1; off < 256; off <<= 1) {
        int x = (t >= off) ? tmp[t - off] : 0;
        __syncthreads();
        tmp[t] += x;
        __syncthreads();
    }
    row_off[i] = tmp[t] - v;
    if (t == 255) bsum[blockIdx.x] = tmp[255];
}

__global__ void k_scanB(int* __restrict__ bsum) {
    __shared__ int tmp[256];
    int t = threadIdx.x;
    int v = bsum[t]; tmp[t] = v; __syncthreads();
    for (int off = 1; off < 256; off <<= 1) {
        int x = (t >= off) ? tmp[t - off] : 0;
        __syncthreads();
        tmp[t] += x;
        __syncthreads();
    }
    bsum[t] = tmp[t] - v;
}

__global__ void k_scanC(int* __restrict__ row_off, const int* __restrict__ bsum, int* __restrict__ cursor) {
    int i = blockIdx.x * 256 + threadIdx.x;
    int v = row_off[i] + bsum[blockIdx.x];
    row_off[i] = v;
    cursor[i] = v;
    if (i == 0) row_off[NN] = TOTE;
}

__global__ void k_scatter(const int* __restrict__ src, const int* __restrict__ dst,
                          const float* __restrict__ ea, const float* __restrict__ sum,
                          int* __restrict__ cursor, int* __restrict__ adj_src,
                          float* __restrict__ adj_ea) {
    int e = blockIdx.x * 256 + threadIdx.x;
    int s, d; float a;
    if (e < NE) { s = src[e]; d = dst[e]; a = ea[e]; }
    else        { s = e - NE; d = s;      a = sum[0] * (1.0f / NE); }
    int pos = atomicAdd(&cursor[d], 1);
    adj_src[pos] = s;
    adj_ea[pos] = a;
}

// ---------- all layers: transpose W (fp32 k-major -> bf16 n-major) ----------
__global__ void k_transpose(const float* __restrict__ Wl, const float* __restrict__ Wr,
                            ushort* __restrict__ WT) {
    // grid (128, 2, 3), block 128
    int k = blockIdx.x, n = threadIdx.x, lr = blockIdx.y, layer = blockIdx.z;
    const float* W = (lr ? Wr : Wl) + layer * 16384;
    WT[(layer * 2 + lr) * 16384 + n * 128 + k] = f2b(W[k * 128 + n]);
}

// ---------- dual GEMM: xl = h@Wl + bl, xr = h@Wr + br  (bf16 MFMA 16x16x32) ----------
#define LDA 136   // bf16 elems per A row in LDS (272B stride, 16B aligned)

__global__ __launch_bounds__(256) void k_gemm(const ushort* __restrict__ hb, const ushort* __restrict__ WT,
                                              const float* __restrict__ bl, const float* __restrict__ br,
                                              ushort* __restrict__ xl, ushort* __restrict__ xr) {
    __shared__ ushort A[64 * LDA];
    int t = threadIdx.x;
    int rowbase = blockIdx.x * 64;

    #pragma unroll
    for (int it = 0; it < 4; it++) {
        int idx = it * 256 + t;          // 1024 chunks of 8 bf16
        int r = idx >> 4, cc = (idx & 15) * 8;
        *(bf16x8*)&A[r * LDA + cc] = *(const bf16x8*)&hb[(size_t)(rowbase + r) * 128 + cc];
    }
    __syncthreads();

    int wave = t >> 6, lane = t & 63;
    int row16 = lane & 15, quad = lane >> 4;

    f32x4 accl[8], accr[8];
    for (int i = 0; i < 8; i++) {
        accl[i] = (f32x4){0.f, 0.f, 0.f, 0.f};
        accr[i] = (f32x4){0.f, 0.f, 0.f, 0.f};
    }

    for (int ks = 0; ks < 4; ks++) {
        bf16x8 a = *(const bf16x8*)&A[(wave * 16 + row16) * LDA + ks * 32 + quad * 8];
        for (int tc = 0; tc < 8; tc++) {
            int coln = tc * 16 + row16;                 // B fragment: n = lane&15
            bf16x8 b_l = *(const bf16x8*)&WT[coln * 128 + ks * 32 + quad * 8];
            bf16x8 b_r = *(const bf16x8*)&WT[16384 + coln * 128 + ks * 32 + quad * 8];
            accl[tc] = __builtin_amdgcn_mfma_f32_16x16x32_bf16(a, b_l, accl[tc], 0, 0, 0);
            accr[tc] = __builtin_amdgcn_mfma_f32_16x16x32_bf16(a, b_r, accr[tc], 0, 0, 0);
        }
    }

    for (int tc = 0; tc < 8; tc++) {
        int col = tc * 16 + row16;                      // C/D: col = lane&15
        float bbl = bl[col], bbr = br[col];
        for (int r = 0; r < 4; r++) {
            int row = rowbase + wave * 16 + quad * 4 + r;   // C/D: row = quad*4 + reg
            size_t o = (size_t)row * 128 + col;
            xl[o] = f2b(accl[tc][r] + bbl);
            xr[o] = f2b(accr[tc][r] + bbr);
        }
    }
}

// ---------- fused attention, single-gather: logits + online softmax + register aggregation ----------
// One wave per node. Lane = (p=lane>>3: edge slot, cl=lane&7: 16-ch block).
// Each 8-edge group: gather rows once (prefetched), logit per lane, head-reduce,
// online-softmax update in registers, weighted-accumulate the SAME registers.
// No LDS / no second gather in the main loop.
template<int H>
__global__ __launch_bounds__(256, 4) void k_attn(
    const ushort* __restrict__ xl, const ushort* __restrict__ xr,
    const int* __restrict__ row_off, const int* __restrict__ adj_src,
    const float* __restrict__ adj_ea,
    const float* __restrict__ We, const float* __restrict__ att,
    const float* __restrict__ bias, const float* __restrict__ ln_g, const float* __restrict__ ln_b,
    float* __restrict__ h, ushort* __restrict__ hb, int apply_gelu)
{
    __shared__ float red_s[4][128];

    int wave = threadIdx.x >> 6, lane = threadIdx.x & 63;
    int n = blockIdx.x * 4 + wave;
    int p = lane >> 3;          // edge slot within 8-edge group
    int cl = lane & 7;          // channel block: ch [16*cl, 16*cl+16)
    int c16 = cl * 16;

    // register caches
    float we[16], at[16], xrl[16];
    #pragma unroll
    for (int k = 0; k < 16; k++) { we[k] = We[c16 + k]; at[k] = att[c16 + k]; }
    {
        bf16x8 r0 = *(const bf16x8*)&xr[(size_t)n * 128 + c16];
        bf16x8 r1 = *(const bf16x8*)&xr[(size_t)n * 128 + c16 + 8];
        #pragma unroll
        for (int k = 0; k < 8; k++) { xrl[k] = (float)r0[k]; xrl[8 + k] = (float)r1[k]; }
    }

    int s0 = row_off[n], s1 = row_off[n + 1];
    int iters = (s1 - s0 + 7) >> 3;

    float m_run = -1e30f, l_run = 0.f;
    float acc[16];
    #pragma unroll
    for (int k = 0; k < 16; k++) acc[k] = 0.f;

    // prefetch group 0
    int j0 = s0 + p;
    int ja = (j0 < s1) ? j0 : s0;
    int sj = adj_src[ja];
    float ea_n = (j0 < s1) ? adj_ea[ja] : 0.f;
    bf16x8 nx0 = *(const bf16x8*)&xl[(size_t)sj * 128 + c16];
    bf16x8 nx1 = *(const bf16x8*)&xl[(size_t)sj * 128 + c16 + 8];

    for (int it = 0; it < iters; ++it) {
        bf16x8 x0 = nx0, x1 = nx1;
        float ea_c = ea_n;
        bool valid = (s0 + it * 8 + p) < s1;

        // prefetch next group
        if (it + 1 < iters) {
            int jn = s0 + (it + 1) * 8 + p;
            int jb = (jn < s1) ? jn : s0;
            int sn = adj_src[jb];
            ea_n = (jn < s1) ? adj_ea[jb] : 0.f;
            nx0 = *(const bf16x8*)&xl[(size_t)sn * 128 + c16];
            nx1 = *(const bf16x8*)&xl[(size_t)sn * 128 + c16 + 8];
        }

        // convert + logit partial over this lane's 16 channels
        float xf[16];
        #pragma unroll
        for (int k = 0; k < 8; k++) { xf[k] = (float)x0[k]; xf[8 + k] = (float)x1[k]; }
        float s = 0.f;
        #pragma unroll
        for (int k = 0; k < 16; k++) {
            float m = xf[k] + fmaf(ea_c, we[k], xrl[k]);
            m = fmaxf(m, 0.2f * m);             // leaky_relu(0.2)
            s = fmaf(m, at[k], s);
        }
        // head reduction across cl lanes of same edge
        s += __shfl_xor(s, 1);
        if (H == 1) { s += __shfl_xor(s, 2); s += __shfl_xor(s, 4); }
        if (!valid) s = -1e30f;

        // per-head max over the 8 edge slots
        float mc = s;
        mc = fmaxf(mc, __shfl_xor(mc, 8));
        mc = fmaxf(mc, __shfl_xor(mc, 16));
        mc = fmaxf(mc, __shfl_xor(mc, 32));
        float nm = fmaxf(m_run, mc);
        float corr = __expf(m_run - nm);
        m_run = nm;
        float e = __expf(s - nm);                // 0 for invalid
        l_run = l_run * corr + e;
        #pragma unroll
        for (int k = 0; k < 16; k++) acc[k] = fmaf(acc[k], corr, e * xf[k]);
    }

    // reduce l and acc over the 8 edge slots (p)
    l_run += __shfl_xor(l_run, 8);
    l_run += __shfl_xor(l_run, 16);
    l_run += __shfl_xor(l_run, 32);
    float inv = 1.0f / (l_run + 1e-16f);
    #pragma unroll
    for (int k = 0; k < 16; k++) {
        acc[k] += __shfl_xor(acc[k], 8);
        acc[k] += __shfl_xor(acc[k], 16);
        acc[k] += __shfl_xor(acc[k], 32);
    }

    // redistribute to 2-channels-per-lane layout via LDS (within-wave)
    if (p == 0) {
        #pragma unroll
        for (int k = 0; k < 16; k += 2)
            *(float2*)&red_s[wave][c16 + k] = make_float2(acc[k] * inv, acc[k + 1] * inv);
    }
    int c0 = 2 * lane;
    float2 ov = *(float2*)&red_s[wave][c0];
    float o0 = ov.x + bias[c0];
    float o1 = ov.y + bias[c0 + 1];

    // LayerNorm over 128 channels (2 per lane)
    float sred = o0 + o1;
    #pragma unroll
    for (int off = 1; off < 64; off <<= 1) sred += __shfl_xor(sred, off);
    float mu = sred * (1.f / 128.f);
    float d0 = o0 - mu, d1 = o1 - mu;
    float v = d0 * d0 + d1 * d1;
    #pragma unroll
    for (int off = 1; off < 64; off <<= 1) v += __shfl_xor(v, off);
    float rstd = rsqrtf(v * (1.f / 128.f) + 1e-5f);
    o0 = d0 * rstd * ln_g[c0] + ln_b[c0];
    o1 = d1 * rstd * ln_g[c0 + 1] + ln_b[c0 + 1];

    if (apply_gelu) {
        o0 = 0.5f * o0 * (1.f + erff(o0 * 0.70710678118f));
        o1 = 0.5f * o1 * (1.f + erff(o1 * 0.70710678118f));
    }

    float2 hv = *(float2*)&h[(size_t)n * 128 + c0];
    hv.x += o0; hv.y += o1;
    *(float2*)&h[(size_t)n * 128 + c0] = hv;
    uint pk = (uint)f2b(hv.x) | ((uint)f2b(hv.y) << 16);
    *(uint*)&hb[(size_t)n * 128 + c0] = pk;
}

// ---------- final: drop last node per graph, emit fp32 ----------
__global__ void k_out(const float* __restrict__ h, float* __restrict__ out) {
    int o = blockIdx.x * 256 + threadIdx.x;   // grid covers 128*511*128 exactly
    int c = o & 127;
    int row = o >> 7;
    int g = row / 511;
    int r = row - g * 511;
    out[o] = h[(size_t)(g * 512 + r) * 128 + c];
}

extern "C" void kernel_launch(void* const* d_in, const int* in_sizes, int n_in,
                              void* d_out, int out_size, void* d_ws, size_t ws_size,
                              hipStream_t stream) {
    const float* x        = (const float*)d_in[0];
    const int*   edge_src = (const int*)d_in[1];
    const int*   edge_dst = (const int*)d_in[2];
    const float* edge_attr= (const float*)d_in[3];
    const float* Wl       = (const float*)d_in[4];
    const float* bl       = (const float*)d_in[5];
    const float* Wr       = (const float*)d_in[6];
    const float* br       = (const float*)d_in[7];
    const float* We       = (const float*)d_in[8];
    const float* att      = (const float*)d_in[9];
    const float* bias_p   = (const float*)d_in[10];
    const float* ln_g     = (const float*)d_in[11];
    const float* ln_b     = (const float*)d_in[12];
    float* out = (float*)d_out;

    char* ws = (char*)d_ws;
    float*  h       = (float*)(ws + 0);                 // 33,554,432
    ushort* hb      = (ushort*)(ws + 33554432);         // 16,777,216
    ushort* xl      = (ushort*)(ws + 50331648);         // 16,777,216
    ushort* xr      = (ushort*)(ws + 67108864);         // 16,777,216
    int*    adj_src = (int*)(ws + 83886080);            //  4,456,448
    float*  adj_ea  = (float*)(ws + 88342528);          //  4,456,448
    int*    row_off = (int*)(ws + 92798976);            //    262,148 (+pad)
    int*    cnt     = (int*)(ws + 93061376);            //    262,144 (also cursor)
    int*    bsum    = (int*)(ws + 93323520);            //      1,024
    float*  sumbuf  = (float*)(ws + 93324544);          //          4 (+pad)
    ushort* WT      = (ushort*)(ws + 93324800);         //    196,608 (3 layers x 2)

    // init
    k_x2hb<<<(NN * DD / 4) / 256, 256, 0, stream>>>((const float4*)x, (float4*)h, hb);
    hipMemsetAsync(cnt, 0, NN * sizeof(int), stream);
    hipMemsetAsync(sumbuf, 0, sizeof(float), stream);
    k_sum<<<256, 256, 0, stream>>>(edge_attr, sumbuf);

    // CSR by dst (edges + self loops)
    k_hist<<<TOTE / 256, 256, 0, stream>>>(edge_dst, cnt);
    k_scanA<<<NN / 256, 256, 0, stream>>>(cnt, row_off, bsum);
    k_scanB<<<1, 256, 0, stream>>>(bsum);
    k_scanC<<<NN / 256, 256, 0, stream>>>(row_off, bsum, cnt);
    k_scatter<<<TOTE / 256, 256, 0, stream>>>(edge_src, edge_dst, edge_attr, sumbuf,
                                              cnt, adj_src, adj_ea);

    // weights for all 3 layers
    k_transpose<<<dim3(128, 2, 3), 128, 0, stream>>>(Wl, Wr, WT);

    // 3 GATv2 layers
    for (int i = 0; i < 3; i++) {
        k_gemm<<<NN / 64, 256, 0, stream>>>(hb, WT + i * 32768, bl + i * 128, br + i * 128, xl, xr);
        if (i < 2) {
            k_attn<4><<<NN / 4, 256, 0, stream>>>(xl, xr, row_off, adj_src, adj_ea,
                                                  We + i * 128, att + i * 128, bias_p + i * 128,
                                                  ln_g + i * 128, ln_b + i * 128, h, hb, 1);
        } else {
            k_attn<1><<<NN / 4, 256, 0, stream>>>(xl, xr, row_off, adj_src, adj_ea,
                                                  We + i * 128, att + i * 128, bias_p + i * 128,
                                                  ln_g + i * 128, ln_b + i * 128, h, hb, 0);
        }
    }

    // output: (128, 511, 128) fp32
    k_out<<<(128 * 511 * 128) / 256, 256, 0, stream>>>(h, out);
}